// Round 10
// baseline (115.429 us; speedup 1.0000x reference)
//
#include <hip/hip_runtime.h>

// Problem constants
#define H_ 96
#define W_ 96
#define HW 9216        // 96*96
#define C_ 64
#define OUTC 64
#define NPTS 9
#define NCH 18
#define B_ 8
#define NPIX 73728     // B*H*W

// LDS patch: 5 rows x 20 cols x 64 ch (padded to 72 shorts) per 16-px strip
#define PCH 72

typedef __attribute__((ext_vector_type(8))) short short8;   // 8 bf16
typedef __attribute__((ext_vector_type(4))) float f32x4;
typedef __attribute__((ext_vector_type(4))) unsigned int uint4v;

__device__ __forceinline__ short f2bf(float f) {
    union { float f; unsigned u; } v; v.f = f;
    unsigned r = v.u + 0x7fffu + ((v.u >> 16) & 1u);   // RNE
    return (short)(r >> 16);
}
__device__ __forceinline__ float bflo(unsigned d) {
    union { unsigned u; float f; } v; v.u = d << 16; return v.f;
}
__device__ __forceinline__ float bfhi(unsigned d) {
    union { unsigned u; float f; } v; v.u = d & 0xffff0000u; return v.f;
}
__device__ __forceinline__ float2 ub2(unsigned d) {
    return make_float2(bflo(d), bfhi(d));
}
__device__ __forceinline__ float2 fma2(float s, float2 a, float2 b) {
    return make_float2(fmaf(s, a.x, b.x), fmaf(s, a.y, b.y));
}

// ---------------- Kernel 1: transpose (4px x 8ch per thread, float4 reads) + weight prep ----------------
__global__ __launch_bounds__(256) void prep_xpose(
    const float* __restrict__ x, const float* __restrict__ w_ker,
    const float* __restrict__ w_off, short* __restrict__ x_t,
    short* __restrict__ wk_frag, short* __restrict__ woff_frag)
{
    int blk = blockIdx.x;
    int t   = threadIdx.x;
    if (blk < 576) {
        int b   = blk & 7;               // image -> XCD pin
        int sub = blk >> 3;              // 0..71 -> 128 px per block
        int cb  = t & 7;                 // 8-channel block
        int px  = sub * 128 + (t >> 3) * 4;

        const float* xp = x + ((size_t)(b * C_ + cb * 8) * HW) + px;
        f32x4 tl[8];
#pragma unroll
        for (int e = 0; e < 8; ++e) tl[e] = *(const f32x4*)(xp + (size_t)e * HW);
#pragma unroll
        for (int p = 0; p < 4; ++p) {
            short8 s;
#pragma unroll
            for (int e = 0; e < 8; ++e) s[e] = f2bf(tl[e][p]);
            *(short8*)(x_t + ((size_t)(b * HW + px + p) * 64) + cb * 8) = s;
        }
    } else {
        int idx = (blk - 576) * 256 + t;            // 0..55295
        if (idx < 36864) {                          // wk_frag: NT=4
            int j = idx & 7, l = (idx >> 3) & 63, nt = (idx >> 9) & 3, sg = idx >> 11;
            int q2 = sg & 1, n = sg >> 1;
            int c  = q2 * 32 + ((l >> 4) << 3) + j;
            int oc = nt * 16 + (l & 15);
            wk_frag[idx] = f2bf(w_ker[(oc * C_ + c) * 9 + n]);
        } else {                                    // woff_frag: NT=2 (18 padded to 32)
            int k = idx - 36864;                    // 0..18431
            int j = k & 7, l = (k >> 3) & 63, nt = (k >> 9) & 1, sg = k >> 10;
            int q2 = sg & 1, n = sg >> 1;
            int c  = q2 * 32 + ((l >> 4) << 3) + j;
            int oc = nt * 16 + (l & 15);
            woff_frag[k] = (oc < NCH) ? f2bf(w_off[(oc * C_ + c) * 9 + n]) : (short)0;
        }
    }
}

// ---------------- Kernel 2: fused offset-conv + deformable sample + GEMM ----------------
// Block = 256 thr (4 waves) = 16-px strip. Phases:
//   stage patch -> bar -> p1 offset-conv (taps 2/2/2/3) -> bar ->
//   reduce: offsets + PRE-COMPUTED bilinear weights/meta per (px,tap) -> bar ->
//   p2 sample+GEMM (taps 2/2/2/3) -> bar -> per-wave partial dump (reuses sX/sE)
//   -> bar -> parallel 4-way sum + bias + store.  5 barriers total.
__global__ __launch_bounds__(256, 7) void deform_fused(
    const short* __restrict__ x_t, const short* __restrict__ woff_frag,
    const float* __restrict__ b_off, const short* __restrict__ wk_frag,
    const float* __restrict__ b_ker, float* __restrict__ out)
{
    __shared__ __align__(16) char smem[22400];
    short* sX = (short*)smem;              // 14400 B: patch [r*20+c][ch(72)]
    float* sE = (float*)(smem + 14400);    //  5120 B: phase-1 partials [px(64)][ch(20)]
    float* sP = (float*)(smem + 19520);    //  2880 B: per (px,tap): w00,w10,w01,w11,meta
    float* sR = (float*)smem;              // epilogue: 4 regions of 1088 floats [px][68]

    int t    = threadIdx.x;
    int lane = t & 63;
    int wv   = t >> 6;                  // 0..3
    int b    = blockIdx.x & 7;          // image -> XCD pin
    int strip= blockIdx.x >> 3;         // 0..575
    int px0  = strip * 16;
    int i    = px0 / W_;                // whole strip on one row (96 % 16 == 0)
    int j0   = px0 - i * W_;
    int pxl  = lane & 15, kq = lane >> 4;
    int j    = j0 + pxl;
    const short* xb = x_t + (size_t)b * HW * 64;
    const short8 Z8 = {0,0,0,0,0,0,0,0};

    // ---- stage the 5x20 patch (clamped source; clamp-equivalent for sampling) ----
    for (int u = t; u < 800; u += 256) {
        int cb = u & 7, rc = u >> 3;         // rc = r*20+c, 0..99
        int r = rc / 20, c = rc - r * 20;
        int row = min(max(i - 2 + r, 0), H_ - 1);
        int col = min(max(j0 - 2 + c, 0), W_ - 1);
        *(short8*)&sX[rc * PCH + cb * 8] =
            *(const short8*)(xb + (row * W_ + col) * 64 + cb * 8);
    }
    __syncthreads();

    // ---- phase 1: offset conv from LDS patch, taps 2/2/2/3 across waves ----
    f32x4 pa0 = {0,0,0,0}, pa1 = {0,0,0,0};
    auto p1tap = [&](int n) {
        int di = n / 3 - 1, dj = n % 3 - 1;
        int ii = i + di, jj = j + dj;
        bool ok = (ii >= 0) & (ii < H_) & (jj >= 0) & (jj < W_);
        int rc = (di + 2) * 20 + (pxl + dj + 2);
#pragma unroll
        for (int q2 = 0; q2 < 2; ++q2) {
            short8 a = *(const short8*)&sX[rc * PCH + q2 * 32 + kq * 8];
            a = ok ? a : Z8;
            const short* wb = woff_frag + ((n * 2 + q2) * 2) * 512 + lane * 8;
            short8 b0 = *(const short8*)(wb);
            short8 b1 = *(const short8*)(wb + 512);
            pa0 = __builtin_amdgcn_mfma_f32_16x16x32_bf16(a, b0, pa0, 0, 0, 0);
            pa1 = __builtin_amdgcn_mfma_f32_16x16x32_bf16(a, b1, pa1, 0, 0, 0);
        }
    };
    if      (wv == 0) { p1tap(0); p1tap(1); }
    else if (wv == 1) { p1tap(2); p1tap(3); }
    else if (wv == 2) { p1tap(4); p1tap(5); }
    else              { p1tap(6); p1tap(7); p1tap(8); }
    {   // partials -> sE: C/D col=lane&15 (=ch), row=(lane>>4)*4+r (=px)
        int col = lane & 15, rq = lane >> 4;
#pragma unroll
        for (int r = 0; r < 4; ++r)
            sE[(wv * 16 + rq * 4 + r) * 20 + col] = pa0[r];
        if (col < 2) {
#pragma unroll
            for (int r = 0; r < 4; ++r)
                sE[(wv * 16 + rq * 4 + r) * 20 + 16 + col] = pa1[r];
        }
    }
    __syncthreads();

    // ---- reduce offsets AND precompute bilinear weights/meta per (px,tap) ----
    if (t < 144) {
        int p = t / 9, n = t - p * 9;
        float ox = sE[p * 20 + n]            + sE[(16 + p) * 20 + n]
                 + sE[(32 + p) * 20 + n]     + sE[(48 + p) * 20 + n]     + b_off[n];
        float oy = sE[p * 20 + 9 + n]        + sE[(16 + p) * 20 + 9 + n]
                 + sE[(32 + p) * 20 + 9 + n] + sE[(48 + p) * 20 + 9 + n] + b_off[9 + n];
        int di = n / 3 - 1, dj = n % 3 - 1;
        float fpx = (float)(i + di) + ox;
        float fpy = (float)(j0 + p + dj) + oy;
        float x0f = floorf(fpx), y0f = floorf(fpy);
        float lx = fpx - x0f, ly = fpy - y0f;
        int xi = (int)x0f, yi = (int)y0f;
        float wx0 = (xi >= 0  && xi <= H_ - 1) ? (1.0f - lx) : 0.0f;
        float wx1 = (xi >= -1 && xi <= H_ - 2) ? lx          : 0.0f;
        float wy0 = (yi >= 0  && yi <= W_ - 1) ? (1.0f - ly) : 0.0f;
        float wy1 = (yi >= -1 && yi <= W_ - 2) ? ly          : 0.0f;
        int rp = xi - (i - 2), cp = yi - (j0 - 2);
        bool inp = (rp >= 0) & (rp <= 3) & (cp >= 0) & (cp <= 18);
        int rc  = inp ? (rp * 20 + cp) : 0;
        int xic = min(max(xi, -3), 100) + 3;     // clamped pack; weights already 0 outside
        int yic = min(max(yi, -3), 100) + 3;
        unsigned meta = (unsigned)rc | ((unsigned)inp << 7)
                      | ((unsigned)xic << 8) | ((unsigned)yic << 15);
        float* pp = &sP[t * 5];
        pp[0] = wx0 * wy0; pp[1] = wx1 * wy0; pp[2] = wx0 * wy1; pp[3] = wx1 * wy1;
        pp[4] = __uint_as_float(meta);
    }
    __syncthreads();

    // ---- phase 2: sample (LDS patch / global fallback) + GEMM, taps 2/2/2/3 ----
    f32x4 acc[4];
#pragma unroll
    for (int nt = 0; nt < 4; ++nt) acc[nt] = (f32x4){0.f, 0.f, 0.f, 0.f};

    auto p2tap = [&](int n) {
        const float* pp = &sP[(pxl * 9 + n) * 5];
        float w00 = pp[0], w10 = pp[1], w01 = pp[2], w11 = pp[3];
        unsigned m = __float_as_uint(pp[4]);
        int rc  = m & 0x7f;
        bool inp = (m >> 7) & 1;
        uint4v u[8];
        if (inp) {   // common path: patch reads (content is clamp-equivalent)
            int l00 = rc * PCH;
            int l10 = l00 + 20 * PCH, l01 = l00 + PCH, l11 = l10 + PCH;
#pragma unroll
            for (int q2 = 0; q2 < 2; ++q2) {
                int cho = q2 * 32 + kq * 8;
                u[q2*4+0] = *(const uint4v*)&sX[l00 + cho];
                u[q2*4+1] = *(const uint4v*)&sX[l10 + cho];
                u[q2*4+2] = *(const uint4v*)&sX[l01 + cho];
                u[q2*4+3] = *(const uint4v*)&sX[l11 + cho];
            }
        }
        if (!inp) {  // rare: |offset| >= 1 -> direct global gather from x_t
            int xi = (int)((m >> 8)  & 0x7f) - 3;
            int yi = (int)((m >> 15) & 0x7f) - 3;
            int r0 = min(max(xi,     0), H_ - 1) * W_;
            int r1 = min(max(xi + 1, 0), H_ - 1) * W_;
            int c0 = min(max(yi,     0), W_ - 1);
            int c1 = min(max(yi + 1, 0), W_ - 1);
#pragma unroll
            for (int q2 = 0; q2 < 2; ++q2) {
                int cho = q2 * 32 + kq * 8;
                u[q2*4+0] = *(const uint4v*)(xb + (r0 + c0) * 64 + cho);
                u[q2*4+1] = *(const uint4v*)(xb + (r1 + c0) * 64 + cho);
                u[q2*4+2] = *(const uint4v*)(xb + (r0 + c1) * 64 + cho);
                u[q2*4+3] = *(const uint4v*)(xb + (r1 + c1) * 64 + cho);
            }
        }
#pragma unroll
        for (int q2 = 0; q2 < 2; ++q2) {
            short8 A;
#pragma unroll
            for (int d = 0; d < 4; ++d) {
                float2 v = make_float2(w00 * bflo(u[q2*4+0][d]), w00 * bfhi(u[q2*4+0][d]));
                v = fma2(w10, ub2(u[q2*4+1][d]), v);
                v = fma2(w01, ub2(u[q2*4+2][d]), v);
                v = fma2(w11, ub2(u[q2*4+3][d]), v);
                A[2 * d]     = f2bf(v.x);
                A[2 * d + 1] = f2bf(v.y);
            }
            const short* wbp = wk_frag + ((n * 2 + q2) * 4) * 512 + lane * 8;
#pragma unroll
            for (int nt = 0; nt < 4; ++nt) {
                short8 bfr = *(const short8*)(wbp + nt * 512);
                acc[nt] = __builtin_amdgcn_mfma_f32_16x16x32_bf16(A, bfr, acc[nt], 0, 0, 0);
            }
        }
    };
    if      (wv == 0) { p2tap(0); p2tap(1); }
    else if (wv == 1) { p2tap(2); p2tap(3); }
    else if (wv == 2) { p2tap(4); p2tap(5); }
    else              { p2tap(6); p2tap(7); p2tap(8); }

    // ---- epilogue: per-wave partial regions (reusing sX/sE), one parallel sum ----
    __syncthreads();                       // all patch/sP reads done; smem reusable
    {
        float* reg = sR + wv * 1088;       // [px][68]
        int col = lane & 15, rq = lane >> 4;
#pragma unroll
        for (int nt = 0; nt < 4; ++nt) {
            int oc = nt * 16 + col;
#pragma unroll
            for (int r = 0; r < 4; ++r)
                reg[(rq * 4 + r) * 68 + oc] = acc[nt][r];
        }
    }
    __syncthreads();
    {
        int oc = t >> 2, qr = t & 3;       // 4 px per thread
        float bias = b_ker[oc];
        f32x4 v;
#pragma unroll
        for (int e = 0; e < 4; ++e) {
            int px = qr * 4 + e;
            v[e] = sR[px * 68 + oc] + sR[1088 + px * 68 + oc]
                 + sR[2176 + px * 68 + oc] + sR[3264 + px * 68 + oc] + bias;
        }
        *(f32x4*)(out + ((size_t)(b * OUTC + oc) * HW) + px0 + qr * 4) = v;
    }
}

extern "C" void kernel_launch(void* const* d_in, const int* in_sizes, int n_in,
                              void* d_out, int out_size, void* d_ws, size_t ws_size,
                              hipStream_t stream) {
    const float* x     = (const float*)d_in[0];
    const float* w_off = (const float*)d_in[1];
    const float* b_off = (const float*)d_in[2];
    const float* w_ker = (const float*)d_in[3];
    const float* b_ker = (const float*)d_in[4];
    float* out = (float*)d_out;

    // workspace: x_t 9,437,184 B | wk_frag 73,728 B | woff_frag 36,864 B
    char*  wsb       = (char*)d_ws;
    short* x_t       = (short*)wsb;
    short* wk_frag   = (short*)(wsb + 9437184);
    short* woff_frag = wk_frag + 36864;

    prep_xpose  <<<792,  256, 0, stream>>>(x, w_ker, w_off, x_t, wk_frag, woff_frag);
    deform_fused<<<4608, 256, 0, stream>>>(x_t, woff_frag, b_off, wk_frag, b_ker, out);
}

// Round 11
// 110.024 us; speedup vs baseline: 1.0491x; 1.0491x over previous
//
#include <hip/hip_runtime.h>

// Problem constants
#define H_ 96
#define W_ 96
#define HW 9216        // 96*96
#define C_ 64
#define OUTC 64
#define NPTS 9
#define NCH 18
#define B_ 8
#define NPIX 73728     // B*H*W

// LDS patch: 5 rows x 20 cols x 64 ch (padded to 72 shorts) per 16-px strip
#define PCH 72

typedef __attribute__((ext_vector_type(8))) short short8;   // 8 bf16
typedef __attribute__((ext_vector_type(4))) float f32x4;
typedef __attribute__((ext_vector_type(4))) unsigned int uint4v;

__device__ __forceinline__ short f2bf(float f) {
    union { float f; unsigned u; } v; v.f = f;
    unsigned r = v.u + 0x7fffu + ((v.u >> 16) & 1u);   // RNE
    return (short)(r >> 16);
}
__device__ __forceinline__ float bflo(unsigned d) {
    union { unsigned u; float f; } v; v.u = d << 16; return v.f;
}
__device__ __forceinline__ float bfhi(unsigned d) {
    union { unsigned u; float f; } v; v.u = d & 0xffff0000u; return v.f;
}

// ---------------- Kernel 1: transpose (4px x 8ch per thread, float4 reads) + weight prep ----------------
__global__ __launch_bounds__(256) void prep_xpose(
    const float* __restrict__ x, const float* __restrict__ w_ker,
    const float* __restrict__ w_off, short* __restrict__ x_t,
    short* __restrict__ wk_frag, short* __restrict__ woff_frag)
{
    int blk = blockIdx.x;
    int t   = threadIdx.x;
    if (blk < 576) {
        int b   = blk & 7;               // image -> XCD pin
        int sub = blk >> 3;              // 0..71 -> 128 px per block
        int cb  = t & 7;                 // 8-channel block
        int px  = sub * 128 + (t >> 3) * 4;

        const float* xp = x + ((size_t)(b * C_ + cb * 8) * HW) + px;
        f32x4 tl[8];
#pragma unroll
        for (int e = 0; e < 8; ++e) tl[e] = *(const f32x4*)(xp + (size_t)e * HW);
#pragma unroll
        for (int p = 0; p < 4; ++p) {
            short8 s;
#pragma unroll
            for (int e = 0; e < 8; ++e) s[e] = f2bf(tl[e][p]);
            *(short8*)(x_t + ((size_t)(b * HW + px + p) * 64) + cb * 8) = s;
        }
    } else {
        int idx = (blk - 576) * 256 + t;            // 0..55295
        if (idx < 36864) {                          // wk_frag: NT=4
            int j = idx & 7, l = (idx >> 3) & 63, nt = (idx >> 9) & 3, sg = idx >> 11;
            int q2 = sg & 1, n = sg >> 1;
            int c  = q2 * 32 + ((l >> 4) << 3) + j;
            int oc = nt * 16 + (l & 15);
            wk_frag[idx] = f2bf(w_ker[(oc * C_ + c) * 9 + n]);
        } else {                                    // woff_frag: NT=2 (18 padded to 32)
            int k = idx - 36864;                    // 0..18431
            int j = k & 7, l = (k >> 3) & 63, nt = (k >> 9) & 1, sg = k >> 10;
            int q2 = sg & 1, n = sg >> 1;
            int c  = q2 * 32 + ((l >> 4) << 3) + j;
            int oc = nt * 16 + (l & 15);
            woff_frag[k] = (oc < NCH) ? f2bf(w_off[(oc * C_ + c) * 9 + n]) : (short)0;
        }
    }
}

// ---------------- Kernel 2: fused offset-conv + deformable sample + GEMM ----------------
// Block = 256 thr (4 waves) = 16-px strip. LDS patch (5x20x64ch bf16) staged from
// x_t; serves phase-1 stencil A-frags and phase-2 bilinear corners (global x_t
// fallback for |offset|>=1 lanes). Taps split 2/2/2/3 across 4 waves in both
// phases; offsets and accumulators reduced through LDS.  (R9 config — best measured.)
__global__ __launch_bounds__(256, 6) void deform_fused(
    const short* __restrict__ x_t, const short* __restrict__ woff_frag,
    const float* __restrict__ b_off, const short* __restrict__ wk_frag,
    const float* __restrict__ b_ker, float* __restrict__ out)
{
    __shared__ __align__(16) short sX[100 * PCH];   // 14400 B: [r*20+c][ch(72)]
    __shared__ float  sE[64 * 20];     // 5120 B: phase-1 partials / epilogue stage
    __shared__ float2 sP[16 * 9];      // 1152 B: per-pixel (ox,oy) per tap

    int t    = threadIdx.x;
    int lane = t & 63;
    int wv   = t >> 6;                  // 0..3
    int b    = blockIdx.x & 7;          // image -> XCD pin
    int strip= blockIdx.x >> 3;         // 0..575
    int px0  = strip * 16;
    int i    = px0 / W_;                // whole strip on one row (96 % 16 == 0)
    int j0   = px0 - i * W_;
    int pxl  = lane & 15, kq = lane >> 4;
    int j    = j0 + pxl;
    const short* xb = x_t + (size_t)b * HW * 64;
    const short8 Z8 = {0,0,0,0,0,0,0,0};

    // ---- stage the 5x20 patch (clamped source; clamp-equivalent for sampling) ----
    for (int u = t; u < 800; u += 256) {
        int cb = u & 7, rc = u >> 3;         // rc = r*20+c, 0..99
        int r = rc / 20, c = rc - r * 20;
        int row = min(max(i - 2 + r, 0), H_ - 1);
        int col = min(max(j0 - 2 + c, 0), W_ - 1);
        *(short8*)&sX[rc * PCH + cb * 8] =
            *(const short8*)(xb + (row * W_ + col) * 64 + cb * 8);
    }
    __syncthreads();

    // ---- phase 1: offset conv from LDS patch, taps 2/2/2/3 across waves ----
    f32x4 pa0 = {0,0,0,0}, pa1 = {0,0,0,0};
    auto p1tap = [&](int n) {
        int di = n / 3 - 1, dj = n % 3 - 1;
        int ii = i + di, jj = j + dj;
        bool ok = (ii >= 0) & (ii < H_) & (jj >= 0) & (jj < W_);
        int rc = (di + 2) * 20 + (pxl + dj + 2);
#pragma unroll
        for (int q2 = 0; q2 < 2; ++q2) {
            short8 a = *(const short8*)&sX[rc * PCH + q2 * 32 + kq * 8];
            a = ok ? a : Z8;
            const short* wb = woff_frag + ((n * 2 + q2) * 2) * 512 + lane * 8;
            short8 b0 = *(const short8*)(wb);
            short8 b1 = *(const short8*)(wb + 512);
            pa0 = __builtin_amdgcn_mfma_f32_16x16x32_bf16(a, b0, pa0, 0, 0, 0);
            pa1 = __builtin_amdgcn_mfma_f32_16x16x32_bf16(a, b1, pa1, 0, 0, 0);
        }
    };
    if      (wv == 0) { p1tap(0); p1tap(1); }
    else if (wv == 1) { p1tap(2); p1tap(3); }
    else if (wv == 2) { p1tap(4); p1tap(5); }
    else              { p1tap(6); p1tap(7); p1tap(8); }
    {   // partials -> LDS: C/D col=lane&15 (=ch), row=(lane>>4)*4+r (=px)
        int col = lane & 15, rq = lane >> 4;
#pragma unroll
        for (int r = 0; r < 4; ++r)
            sE[(wv * 16 + rq * 4 + r) * 20 + col] = pa0[r];
        if (col < 2) {
#pragma unroll
            for (int r = 0; r < 4; ++r)
                sE[(wv * 16 + rq * 4 + r) * 20 + 16 + col] = pa1[r];
        }
    }
    __syncthreads();

    // ---- reduce 4 partials + bias -> per-pixel offset pair table ----
    if (t < 144) {
        int p = t / 9, n = t - p * 9;
        float ox = sE[p * 20 + n]             + sE[(16 + p) * 20 + n]
                 + sE[(32 + p) * 20 + n]      + sE[(48 + p) * 20 + n]      + b_off[n];
        float oy = sE[p * 20 + 9 + n]         + sE[(16 + p) * 20 + 9 + n]
                 + sE[(32 + p) * 20 + 9 + n]  + sE[(48 + p) * 20 + 9 + n]  + b_off[9 + n];
        sP[p * 9 + n] = make_float2(ox, oy);
    }
    __syncthreads();

    // ---- phase 2: sample (LDS patch, global fallback) + GEMM, taps 2/2/2/3 ----
    f32x4 acc[4];
#pragma unroll
    for (int nt = 0; nt < 4; ++nt) acc[nt] = (f32x4){0.f, 0.f, 0.f, 0.f};

    auto p2tap = [&](int n) {
        int di = n / 3 - 1, dj = n % 3 - 1;
        float2 o = sP[pxl * 9 + n];
        float fpx = (float)(i + di) + o.x;
        float fpy = (float)(j + dj) + o.y;
        float x0f = floorf(fpx), y0f = floorf(fpy);
        float lx = fpx - x0f, ly = fpy - y0f;
        int xi = (int)x0f, yi = (int)y0f;
        float wx0 = (xi >= 0  && xi <= H_ - 1) ? (1.0f - lx) : 0.0f;
        float wx1 = (xi >= -1 && xi <= H_ - 2) ? lx          : 0.0f;
        float wy0 = (yi >= 0  && yi <= W_ - 1) ? (1.0f - ly) : 0.0f;
        float wy1 = (yi >= -1 && yi <= W_ - 2) ? ly          : 0.0f;
        float w00 = wx0 * wy0, w10 = wx1 * wy0, w01 = wx0 * wy1, w11 = wx1 * wy1;
        int rp = xi - (i - 2), cp = yi - (j0 - 2);
        bool inp = (rp >= 0) & (rp <= 3) & (cp >= 0) & (cp <= 18);
        uint4v u[8];
        if (inp) {   // common path: patch reads (content is clamp-equivalent)
            int l00 = (rp * 20 + cp) * PCH;
            int l10 = l00 + 20 * PCH, l01 = l00 + PCH, l11 = l10 + PCH;
#pragma unroll
            for (int q2 = 0; q2 < 2; ++q2) {
                int cho = q2 * 32 + kq * 8;
                u[q2*4+0] = *(const uint4v*)&sX[l00 + cho];
                u[q2*4+1] = *(const uint4v*)&sX[l10 + cho];
                u[q2*4+2] = *(const uint4v*)&sX[l01 + cho];
                u[q2*4+3] = *(const uint4v*)&sX[l11 + cho];
            }
        }
        if (!inp) {  // rare: |offset| >= 1 -> direct global gather from x_t
            int r0 = min(max(xi,     0), H_ - 1) * W_;
            int r1 = min(max(xi + 1, 0), H_ - 1) * W_;
            int c0 = min(max(yi,     0), W_ - 1);
            int c1 = min(max(yi + 1, 0), W_ - 1);
#pragma unroll
            for (int q2 = 0; q2 < 2; ++q2) {
                int cho = q2 * 32 + kq * 8;
                u[q2*4+0] = *(const uint4v*)(xb + (r0 + c0) * 64 + cho);
                u[q2*4+1] = *(const uint4v*)(xb + (r1 + c0) * 64 + cho);
                u[q2*4+2] = *(const uint4v*)(xb + (r0 + c1) * 64 + cho);
                u[q2*4+3] = *(const uint4v*)(xb + (r1 + c1) * 64 + cho);
            }
        }
#pragma unroll
        for (int q2 = 0; q2 < 2; ++q2) {
            short8 A;
#pragma unroll
            for (int d = 0; d < 4; ++d) {
                float lo = w00 * bflo(u[q2*4+0][d]) + w10 * bflo(u[q2*4+1][d])
                         + w01 * bflo(u[q2*4+2][d]) + w11 * bflo(u[q2*4+3][d]);
                float hi = w00 * bfhi(u[q2*4+0][d]) + w10 * bfhi(u[q2*4+1][d])
                         + w01 * bfhi(u[q2*4+2][d]) + w11 * bfhi(u[q2*4+3][d]);
                A[2 * d]     = f2bf(lo);
                A[2 * d + 1] = f2bf(hi);
            }
            const short* wbp = wk_frag + ((n * 2 + q2) * 4) * 512 + lane * 8;
#pragma unroll
            for (int nt = 0; nt < 4; ++nt) {
                short8 bfr = *(const short8*)(wbp + nt * 512);
                acc[nt] = __builtin_amdgcn_mfma_f32_16x16x32_bf16(A, bfr, acc[nt], 0, 0, 0);
            }
        }
    };
    if      (wv == 0) { p2tap(0); p2tap(1); }
    else if (wv == 1) { p2tap(2); p2tap(3); }
    else if (wv == 2) { p2tap(4); p2tap(5); }
    else              { p2tap(6); p2tap(7); p2tap(8); }

    // ---- epilogue: 4-step cross-wave reduce in LDS, then coalesced stores ----
    __syncthreads();
    int col = lane & 15, rq = lane >> 4;
    if (wv == 0) {
#pragma unroll
        for (int nt = 0; nt < 4; ++nt) {
            int oc = nt * 16 + col;
            float bias = b_ker[oc];
#pragma unroll
            for (int r = 0; r < 4; ++r)
                sE[oc * 20 + rq * 4 + r] = acc[nt][r] + bias;
        }
    }
    __syncthreads();
    if (wv == 1) {
#pragma unroll
        for (int nt = 0; nt < 4; ++nt) {
            int oc = nt * 16 + col;
#pragma unroll
            for (int r = 0; r < 4; ++r)
                sE[oc * 20 + rq * 4 + r] += acc[nt][r];
        }
    }
    __syncthreads();
    if (wv == 2) {
#pragma unroll
        for (int nt = 0; nt < 4; ++nt) {
            int oc = nt * 16 + col;
#pragma unroll
            for (int r = 0; r < 4; ++r)
                sE[oc * 20 + rq * 4 + r] += acc[nt][r];
        }
    }
    __syncthreads();
    if (wv == 3) {
#pragma unroll
        for (int nt = 0; nt < 4; ++nt) {
            int oc = nt * 16 + col;
#pragma unroll
            for (int r = 0; r < 4; ++r)
                sE[oc * 20 + rq * 4 + r] += acc[nt][r];
        }
    }
    __syncthreads();

    int oc = t >> 2, qr = t & 3;
    const float* se = &sE[oc * 20 + qr * 4];
    float* outp = out + ((size_t)(b * OUTC + oc) * HW) + px0 + qr * 4;
    *(f32x4*)outp = *(const f32x4*)se;
}

extern "C" void kernel_launch(void* const* d_in, const int* in_sizes, int n_in,
                              void* d_out, int out_size, void* d_ws, size_t ws_size,
                              hipStream_t stream) {
    const float* x     = (const float*)d_in[0];
    const float* w_off = (const float*)d_in[1];
    const float* b_off = (const float*)d_in[2];
    const float* w_ker = (const float*)d_in[3];
    const float* b_ker = (const float*)d_in[4];
    float* out = (float*)d_out;

    // workspace: x_t 9,437,184 B | wk_frag 73,728 B | woff_frag 36,864 B
    char*  wsb       = (char*)d_ws;
    short* x_t       = (short*)wsb;
    short* wk_frag   = (short*)(wsb + 9437184);
    short* woff_frag = wk_frag + 36864;

    prep_xpose  <<<792,  256, 0, stream>>>(x, w_ker, w_off, x_t, wk_frag, woff_frag);
    deform_fused<<<4608, 256, 0, stream>>>(x_t, woff_frag, b_off, wk_frag, b_ker, out);
}